// Round 12
// baseline (168.603 us; speedup 1.0000x reference)
//
#include <hip/hip_runtime.h>

// Neo-Hookean constants (match reference)
#define MU_C   3846.1538461538462f   // E/(2(1+nu))
#define LM_C   5769.2307692307695f   // E*nu/((1+nu)(1-2nu))
#define LOGC   (MU_C + 0.5f * LM_C)  // combined log coefficient
#define EPS_C  1e-10f

// R11: ablation round. Five single-variable variants of the v2-structure
// kernel (thread=(element,batch), padded-ut float4 gather, 7813 blocks).
// MODE 0=full(real output) 1=loads-only 2=VALU-only 3=no-gather 4=no-dN.
// Ablation outputs go to dead scratch; only MODE 0 feeds nh_final.

// Transpose u (B, n_nodes, 3) -> ut (n_nodes, B, 4) padded float4 (64B/node).
__global__ __launch_bounds__(256) void nh_transpose_u_pad(
    const float* __restrict__ u, float4* __restrict__ ut, int n_nodes)
{
    const int i = blockIdx.x * 256 + threadIdx.x;
    if (i >= n_nodes) return;
    float4* q = ut + (size_t)i * 4;
    #pragma unroll
    for (int b = 0; b < 4; ++b) {
        const float* p = u + ((size_t)b * n_nodes + i) * 3;
        q[b] = make_float4(p[0], p[1], p[2], 0.f);
    }
}

// energy of one element/batch from registers
__device__ __forceinline__ float nh_energy(
    const float4* dn, const float4* uu, const float* wqv)
{
    const float* d  = reinterpret_cast<const float*>(dn);   // d[(q*4+n)*3+j]
    const float* us = reinterpret_cast<const float*>(uu);
    float a = 0.f;
    #pragma unroll
    for (int q = 0; q < 4; ++q) {
        float F[3][3];
        #pragma unroll
        for (int i = 0; i < 3; ++i) {
            #pragma unroll
            for (int j = 0; j < 3; ++j) {
                float g = 0.f;
                #pragma unroll
                for (int n = 0; n < 4; ++n)
                    g = fmaf(us[n * 4 + i], d[(q*4 + n)*3 + j], g);
                F[i][j] = g + ((i == j) ? 1.f : 0.f);
            }
        }
        const float J =
              F[0][0] * (F[1][1]*F[2][2] - F[1][2]*F[2][1])
            - F[0][1] * (F[1][0]*F[2][2] - F[1][2]*F[2][0])
            + F[0][2] * (F[1][0]*F[2][1] - F[1][1]*F[2][0]);
        float IC = 0.f;
        #pragma unroll
        for (int i = 0; i < 3; ++i)
            #pragma unroll
            for (int j = 0; j < 3; ++j)
                IC = fmaf(F[i][j], F[i][j], IC);
        const float lj = __logf(fmaxf(J, EPS_C));
        const float W = 0.5f * MU_C * (IC - 3.f)
                      + 0.25f * LM_C * fmaf(J, J, -1.f)
                      - LOGC * lj;
        a = fmaf(W, wqv[q], a);
    }
    return a;
}

template<int MODE>
__global__ __launch_bounds__(256) void nh_ab(
    const float4* __restrict__ ut,        // (n_nodes, 4) padded float4
    const int4*   __restrict__ elp,       // (n_elem)
    const float4* __restrict__ dnp,       // (n_elem*12)
    const float4* __restrict__ djp,       // (n_elem)
    const float*  __restrict__ qw,        // (4,)
    float* __restrict__ partial,          // (gridDim.x, 4)
    int n_elem)
{
    const int t = blockIdx.x * 256 + threadIdx.x;
    const int e = t >> 2;
    const int b = t & 3;

    float acc = 0.f;

    if (e < n_elem) {
        const float4 w4 = *reinterpret_cast<const float4*>(qw);
        int4 nd; float4 dj; float4 dv[12]; float4 uu[4];

        if constexpr (MODE == 2) {
            // VALU-only: synthesize all inputs from indices, zero global loads
            nd = make_int4(e & 1023, (e >> 1) & 1023, (e >> 2) & 1023, (e >> 3) & 1023);
            dj = make_float4(e * 1e-6f, e * 2e-6f, e * 3e-6f, b * 1e-6f);
            #pragma unroll
            for (int k = 0; k < 12; ++k)
                dv[k] = make_float4(k * 1e-3f, e * 1e-7f, b * 1e-2f, 1e-3f);
            #pragma unroll
            for (int n = 0; n < 4; ++n)
                uu[n] = make_float4(n * 1e-3f, e * 1e-8f, b * 1e-3f, 0.f);
        } else {
            nd = elp[e];
            dj = djp[e];
            if constexpr (MODE != 4) {
                const float4* dptr = dnp + (size_t)e * 12;
                #pragma unroll
                for (int k = 0; k < 12; ++k) dv[k] = dptr[k];
            } else {
                // no-dN: synthesize slab (nd kept live through it)
                #pragma unroll
                for (int k = 0; k < 12; ++k)
                    dv[k] = make_float4(nd.x * 1e-8f, k * 1e-3f, b * 1e-2f, 1e-3f);
            }
            if constexpr (MODE != 3) {
                uu[0] = ut[nd.x * 4 + b];
                uu[1] = ut[nd.y * 4 + b];
                uu[2] = ut[nd.z * 4 + b];
                uu[3] = ut[nd.w * 4 + b];
            } else {
                // no-gather: synthesize u (nd kept live through it)
                #pragma unroll
                for (int n = 0; n < 4; ++n)
                    uu[n] = make_float4(nd.x * 1e-8f, nd.y * 1e-8f, nd.z * 1e-8f, 0.f);
            }
        }

        const float wq[4] = {dj.x * w4.x, dj.y * w4.y, dj.z * w4.z, dj.w * w4.w};

        if constexpr (MODE == 1) {
            // loads-only: consume everything with minimal VALU
            float s = 0.f;
            #pragma unroll
            for (int k = 0; k < 12; ++k)
                s += dv[k].x + dv[k].y + dv[k].z + dv[k].w;
            #pragma unroll
            for (int n = 0; n < 4; ++n)
                s += uu[n].x + uu[n].y + uu[n].z;
            acc = fmaf(s, wq[0], wq[1] + wq[2] + wq[3]);
        } else {
            acc = nh_energy(dv, uu, wq);
        }
    }

    // reduce across lanes with the same b (stride-4 groups)
    #pragma unroll
    for (int off = 32; off >= 4; off >>= 1)
        acc += __shfl_down(acc, off);

    __shared__ float s_red[4][4];
    const int lane = threadIdx.x & 63;
    const int wid  = threadIdx.x >> 6;
    if (lane < 4) s_red[wid][lane] = acc;
    __syncthreads();
    if (threadIdx.x < 4)
        partial[(size_t)blockIdx.x * 4 + threadIdx.x] =
            (s_red[0][threadIdx.x] + s_red[1][threadIdx.x]) +
            (s_red[2][threadIdx.x] + s_red[3][threadIdx.x]);
}

__global__ __launch_bounds__(256) void nh_final(
    const float* __restrict__ partial, float* __restrict__ out, int nparts)
{
    float accb[4] = {0.f, 0.f, 0.f, 0.f};
    for (int i = threadIdx.x; i < nparts; i += 256) {
        const float4 p = reinterpret_cast<const float4*>(partial)[i];
        accb[0] += p.x; accb[1] += p.y; accb[2] += p.z; accb[3] += p.w;
    }
    #pragma unroll
    for (int b = 0; b < 4; ++b) {
        float v = accb[b];
        #pragma unroll
        for (int off = 32; off > 0; off >>= 1)
            v += __shfl_down(v, off);
        accb[b] = v;
    }
    __shared__ float lds[4][4];
    const int lane = threadIdx.x & 63;
    const int wid  = threadIdx.x >> 6;
    if (lane == 0) {
        #pragma unroll
        for (int b = 0; b < 4; ++b) lds[wid][b] = accb[b];
    }
    __syncthreads();
    if (threadIdx.x == 0) {
        #pragma unroll
        for (int b = 0; b < 4; ++b)
            out[b] = (lds[0][b] + lds[1][b]) + (lds[2][b] + lds[3][b]);
    }
}

extern "C" void kernel_launch(void* const* d_in, const int* in_sizes, int n_in,
                              void* d_out, int out_size, void* d_ws, size_t ws_size,
                              hipStream_t stream) {
    const float* u        = (const float*)d_in[0];
    const int*   elements = (const int*)d_in[1];
    const float* dN_dx    = (const float*)d_in[2];
    const float* detJ     = (const float*)d_in[3];
    const float* qw       = (const float*)d_in[4];
    float* out = (float*)d_out;

    const int B       = out_size;            // 4
    const int n_nodes = in_sizes[0] / (3 * B);
    const int n_elem  = in_sizes[1] / 4;

    const int threads = 256;
    const int nblocks = (n_elem * 4 + threads - 1) / threads;

    const size_t ut_bytes   = (size_t)n_nodes * 4 * sizeof(float4);
    const size_t part_bytes = (size_t)nblocks * 4 * sizeof(float);

    float4* ut       = (float4*)d_ws;
    float*  partial0 = (float*)((char*)d_ws + ut_bytes);                  // real
    float*  scratch  = (float*)((char*)d_ws + ut_bytes + part_bytes);     // dead

    const int4*   elp = reinterpret_cast<const int4*>(elements);
    const float4* dnp = reinterpret_cast<const float4*>(dN_dx);
    const float4* djp = reinterpret_cast<const float4*>(detJ);

    const int tb = (n_nodes + threads - 1) / threads;
    nh_transpose_u_pad<<<tb, threads, 0, stream>>>(u, ut, n_nodes);

    // real result
    nh_ab<0><<<nblocks, threads, 0, stream>>>(ut, elp, dnp, djp, qw, partial0, n_elem);
    // ablations (scratch, dead output — diagnosis via rocprof per-dispatch rows)
    nh_ab<1><<<nblocks, threads, 0, stream>>>(ut, elp, dnp, djp, qw, scratch, n_elem);
    nh_ab<2><<<nblocks, threads, 0, stream>>>(ut, elp, dnp, djp, qw, scratch, n_elem);
    nh_ab<3><<<nblocks, threads, 0, stream>>>(ut, elp, dnp, djp, qw, scratch, n_elem);
    nh_ab<4><<<nblocks, threads, 0, stream>>>(ut, elp, dnp, djp, qw, scratch, n_elem);

    nh_final<<<1, threads, 0, stream>>>(partial0, out, nblocks);
}

// Round 13
// 113.576 us; speedup vs baseline: 1.4845x; 1.4845x over previous
//
#include <hip/hip_runtime.h>

// Neo-Hookean constants (match reference)
#define MU_C   3846.1538461538462f   // E/(2(1+nu))
#define LM_C   5769.2307692307695f   // E*nu/((1+nu)(1-2nu))
#define LOGC   (MU_C + 0.5f * LM_C)  // combined log coefficient
#define EPS_C  1e-10f

// native vector types (required for __builtin_nontemporal_load)
typedef float nf4 __attribute__((ext_vector_type(4)));
typedef int   ni4 __attribute__((ext_vector_type(4)));

// v13 = v3 structure (best measured: LDS-staged dN, fully-coalesced 1KB/instr)
//       + T1 XCD-aware bijective block swizzle (each XCD gets a contiguous
//         element range -> DRAM page / L2 locality)
//       + nontemporal on the 96MB dN stream (preserve L3 for the ut gather).
// Plus nh_readsum: ideal-pattern pure-read probe (4 x 96MB) as roofline anchor.
#define ELB 64          // elements per block
#define SLAB 52         // padded floats per element slab (bank stride 20 -> 2-way max)

// Transpose u (B, n_nodes, 3) -> ut (n_nodes, B, 4) padded float4 (64B/node).
__global__ __launch_bounds__(256) void nh_transpose_u_pad(
    const float* __restrict__ u, float4* __restrict__ ut, int n_nodes)
{
    const int i = blockIdx.x * 256 + threadIdx.x;
    if (i >= n_nodes) return;
    float4* q = ut + (size_t)i * 4;
    #pragma unroll
    for (int b = 0; b < 4; ++b) {
        const float* p = u + ((size_t)b * n_nodes + i) * 3;
        q[b] = make_float4(p[0], p[1], p[2], 0.f);
    }
}

__global__ __launch_bounds__(256) void nh_partial_v13(
    const float4* __restrict__ ut,        // (n_nodes, 4) padded float4
    const int*   __restrict__ elements,   // (n_elem, 4)
    const float* __restrict__ dN_dx,      // (n_elem, 4, 4, 3)
    const float* __restrict__ detJ,       // (n_elem, 4)
    const float* __restrict__ qw,         // (4,)
    float* __restrict__ partial,          // (gridDim.x, 4)
    int n_elem)
{
    __shared__ float s_dn[ELB * SLAB];    // 13312 B
    __shared__ int   s_el[ELB * 4];       // 1024 B
    __shared__ float s_dj[ELB * 4];       // 1024 B
    __shared__ float s_red[4][4];

    const int t = threadIdx.x;

    // ---- T1: XCD-aware bijective swizzle (m204): physical block P -> tile ----
    // XCD k processes a contiguous chunk of tiles -> contiguous dN region.
    const int nwg = gridDim.x;
    const int P   = blockIdx.x;
    const int xcd = P & 7;
    const int j   = P >> 3;
    const int q8  = nwg >> 3;
    const int r8  = nwg & 7;
    const int tile = ((xcd < r8) ? xcd * (q8 + 1) : r8 * (q8 + 1) + (xcd - r8) * q8) + j;

    const int e0  = tile * ELB;
    const int rem = min(ELB, n_elem - e0);

    // ---- stage dN_dx: rem*12 float4s, fully coalesced, nontemporal ----
    {
        const nf4* src = reinterpret_cast<const nf4*>(dN_dx) + (size_t)e0 * 12;
        const int nf4n = rem * 12;
        #pragma unroll
        for (int jj = 0; jj < 3; ++jj) {
            const int m = t + 256 * jj;
            if (m < nf4n) {
                const nf4 v = __builtin_nontemporal_load(src + m);
                *reinterpret_cast<nf4*>(&s_dn[(m / 12) * SLAB + (m % 12) * 4]) = v;
            }
        }
    }
    // ---- stage elements (wave 0) and detJ (wave 1), coalesced, nontemporal ----
    if (t < 64) {
        if (t < rem) {
            const ni4 v = __builtin_nontemporal_load(
                reinterpret_cast<const ni4*>(elements) + e0 + t);
            reinterpret_cast<ni4*>(s_el)[t] = v;
        }
    } else if (t < 128) {
        const int i = t - 64;
        if (i < rem) {
            const nf4 v = __builtin_nontemporal_load(
                reinterpret_cast<const nf4*>(detJ) + e0 + i);
            reinterpret_cast<nf4*>(s_dj)[i] = v;
        }
    }
    __syncthreads();

    const int el = t >> 2;
    const int b  = t & 3;
    float a = 0.f;

    if (el < rem) {
        const int4 nd = reinterpret_cast<const int4*>(s_el)[el];

        // gather u: one dwordx4 per node; 4 batch-lanes cover one 64B line (cached)
        float eu[4][3];
        {
            const float4 v0 = ut[(size_t)nd.x * 4 + b];
            const float4 v1 = ut[(size_t)nd.y * 4 + b];
            const float4 v2 = ut[(size_t)nd.z * 4 + b];
            const float4 v3 = ut[(size_t)nd.w * 4 + b];
            eu[0][0]=v0.x; eu[0][1]=v0.y; eu[0][2]=v0.z;
            eu[1][0]=v1.x; eu[1][1]=v1.y; eu[1][2]=v1.z;
            eu[2][0]=v2.x; eu[2][1]=v2.y; eu[2][2]=v2.z;
            eu[3][0]=v3.x; eu[3][1]=v3.y; eu[3][2]=v3.z;
        }

        const float4 w4 = *reinterpret_cast<const float4*>(qw);
        const float* dj = &s_dj[el * 4];
        const float wq[4] = {dj[0]*w4.x, dj[1]*w4.y, dj[2]*w4.z, dj[3]*w4.w};

        const float* slab = &s_dn[el * SLAB];
        #pragma unroll
        for (int q = 0; q < 4; ++q) {
            const float4 f0 = *reinterpret_cast<const float4*>(slab + q*12 + 0);
            const float4 f1 = *reinterpret_cast<const float4*>(slab + q*12 + 4);
            const float4 f2 = *reinterpret_cast<const float4*>(slab + q*12 + 8);
            const float d[12] = {f0.x,f0.y,f0.z,f0.w, f1.x,f1.y,f1.z,f1.w,
                                 f2.x,f2.y,f2.z,f2.w};   // d[n*3 + j]

            float F[3][3];
            #pragma unroll
            for (int i = 0; i < 3; ++i) {
                #pragma unroll
                for (int jj = 0; jj < 3; ++jj) {
                    float g = 0.f;
                    #pragma unroll
                    for (int n = 0; n < 4; ++n)
                        g = fmaf(eu[n][i], d[n*3 + jj], g);
                    F[i][jj] = g + ((i == jj) ? 1.f : 0.f);
                }
            }
            const float J =
                  F[0][0] * (F[1][1]*F[2][2] - F[1][2]*F[2][1])
                - F[0][1] * (F[1][0]*F[2][2] - F[1][2]*F[2][0])
                + F[0][2] * (F[1][0]*F[2][1] - F[1][1]*F[2][0]);

            float IC = 0.f;
            #pragma unroll
            for (int i = 0; i < 3; ++i)
                #pragma unroll
                for (int jj = 0; jj < 3; ++jj)
                    IC = fmaf(F[i][jj], F[i][jj], IC);

            const float lj = __logf(fmaxf(J, EPS_C));
            const float W = 0.5f * MU_C * (IC - 3.f)
                          + 0.25f * LM_C * fmaf(J, J, -1.f)
                          - LOGC * lj;
            a = fmaf(W, wq[q], a);
        }
    }

    // reduce across lanes with same b (stride-4 groups)
    #pragma unroll
    for (int off = 32; off >= 4; off >>= 1)
        a += __shfl_down(a, off);

    const int lane = t & 63;
    const int wid  = t >> 6;
    if (lane < 4) s_red[wid][lane] = a;
    __syncthreads();
    if (t < 4)
        partial[(size_t)P * 4 + t] =
            (s_red[0][t] + s_red[1][t]) + (s_red[2][t] + s_red[3][t]);
}

// Roofline anchor: ideal-pattern pure read of dN_dx, 4 passes (384MB), nt loads.
__global__ __launch_bounds__(256) void nh_readsum(
    const float* __restrict__ dN_dx, float* __restrict__ scratch, int nf4n)
{
    const nf4* src = reinterpret_cast<const nf4*>(dN_dx);
    float s = 0.f;
    #pragma unroll
    for (int pass = 0; pass < 4; ++pass) {
        for (int i = blockIdx.x * 256 + threadIdx.x; i < nf4n; i += 2048 * 256) {
            const nf4 v = __builtin_nontemporal_load(src + i);
            s += v.x + v.y + v.z + v.w;
        }
    }
    #pragma unroll
    for (int off = 32; off > 0; off >>= 1)
        s += __shfl_down(s, off);
    __shared__ float r[4];
    if ((threadIdx.x & 63) == 0) r[threadIdx.x >> 6] = s;
    __syncthreads();
    if (threadIdx.x == 0)
        scratch[blockIdx.x] = (r[0] + r[1]) + (r[2] + r[3]);
}

__global__ __launch_bounds__(256) void nh_final(
    const float* __restrict__ partial, float* __restrict__ out, int nparts)
{
    float accb[4] = {0.f, 0.f, 0.f, 0.f};
    for (int i = threadIdx.x; i < nparts; i += 256) {
        const float4 p = reinterpret_cast<const float4*>(partial)[i];
        accb[0] += p.x; accb[1] += p.y; accb[2] += p.z; accb[3] += p.w;
    }
    #pragma unroll
    for (int b = 0; b < 4; ++b) {
        float v = accb[b];
        #pragma unroll
        for (int off = 32; off > 0; off >>= 1)
            v += __shfl_down(v, off);
        accb[b] = v;
    }
    __shared__ float lds[4][4];
    const int lane = threadIdx.x & 63;
    const int wid  = threadIdx.x >> 6;
    if (lane == 0) {
        #pragma unroll
        for (int b = 0; b < 4; ++b) lds[wid][b] = accb[b];
    }
    __syncthreads();
    if (threadIdx.x == 0) {
        #pragma unroll
        for (int b = 0; b < 4; ++b)
            out[b] = (lds[0][b] + lds[1][b]) + (lds[2][b] + lds[3][b]);
    }
}

extern "C" void kernel_launch(void* const* d_in, const int* in_sizes, int n_in,
                              void* d_out, int out_size, void* d_ws, size_t ws_size,
                              hipStream_t stream) {
    const float* u        = (const float*)d_in[0];
    const int*   elements = (const int*)d_in[1];
    const float* dN_dx    = (const float*)d_in[2];
    const float* detJ     = (const float*)d_in[3];
    const float* qw       = (const float*)d_in[4];
    float* out = (float*)d_out;

    const int B       = out_size;            // 4
    const int n_nodes = in_sizes[0] / (3 * B);
    const int n_elem  = in_sizes[1] / 4;

    const int threads = 256;
    const int nblocks = (n_elem + ELB - 1) / ELB;

    const size_t ut_bytes   = (size_t)n_nodes * 4 * sizeof(float4);
    const size_t part_bytes = (size_t)nblocks * 4 * sizeof(float);

    float4* ut      = (float4*)d_ws;
    float*  partial = (float*)((char*)d_ws + ut_bytes);
    float*  scratch = (float*)((char*)d_ws + ut_bytes + part_bytes);  // dead (probe)

    const int tb = (n_nodes + threads - 1) / threads;
    nh_transpose_u_pad<<<tb, threads, 0, stream>>>(u, ut, n_nodes);

    nh_partial_v13<<<nblocks, threads, 0, stream>>>(ut, elements, dN_dx, detJ, qw,
                                                    partial, n_elem);

    // roofline anchor (output dead, deterministic)
    nh_readsum<<<2048, threads, 0, stream>>>(dN_dx, scratch, n_elem * 12);

    nh_final<<<1, threads, 0, stream>>>(partial, out, nblocks);
}

// Round 14
// 58.023 us; speedup vs baseline: 2.9058x; 1.9574x over previous
//
#include <hip/hip_runtime.h>

// Neo-Hookean constants (match reference)
#define MU_C   3846.1538461538462f   // E/(2(1+nu))
#define LM_C   5769.2307692307695f   // E*nu/((1+nu)(1-2nu))
#define LOGC   (MU_C + 0.5f * LM_C)  // combined log coefficient
#define EPS_C  1e-10f

// native vector types (required for __builtin_nontemporal_load)
typedef float nf4 __attribute__((ext_vector_type(4)));
typedef int   ni4 __attribute__((ext_vector_type(4)));

// R13 = v13 clean: v3 structure (LDS-staged dN, coalesced 1KB/instr) +
// exact-bijective XCD swizzle (grid padded to %8==0) + nontemporal stream
// loads (preserve L2/L3 for the 6.4MB ut gather table) + 32-bit gather math.
#define ELB 64          // elements per block
#define SLAB 52         // padded floats per element slab (bank stride 20 -> 2-way max)

// Transpose u (B, n_nodes, 3) -> ut (n_nodes, B, 4) padded float4 (64B/node).
__global__ __launch_bounds__(256) void nh_transpose_u_pad(
    const float* __restrict__ u, float4* __restrict__ ut, int n_nodes)
{
    const int i = blockIdx.x * 256 + threadIdx.x;
    if (i >= n_nodes) return;
    float4* q = ut + (size_t)i * 4;
    #pragma unroll
    for (int b = 0; b < 4; ++b) {
        const float* p = u + ((size_t)b * n_nodes + i) * 3;
        q[b] = make_float4(p[0], p[1], p[2], 0.f);
    }
}

__global__ __launch_bounds__(256) void nh_partial_v14(
    const float4* __restrict__ ut,        // (n_nodes, 4) padded float4
    const int*   __restrict__ elements,   // (n_elem, 4)
    const float* __restrict__ dN_dx,      // (n_elem, 4, 4, 3)
    const float* __restrict__ detJ,       // (n_elem, 4)
    const float* __restrict__ qw,         // (4,)
    float* __restrict__ partial,          // (gridDim.x, 4)
    int n_elem)
{
    __shared__ float s_dn[ELB * SLAB];    // 13312 B
    __shared__ int   s_el[ELB * 4];       // 1024 B
    __shared__ float s_dj[ELB * 4];       // 1024 B
    __shared__ float s_red[4][4];

    const int t = threadIdx.x;

    // ---- exact bijective XCD swizzle: gridDim.x % 8 == 0 guaranteed ----
    // physical block P -> XCD (P&7) processes contiguous tile chunk.
    const int P    = blockIdx.x;
    const int cpx  = gridDim.x >> 3;          // chunk per XCD
    const int tile = (P & 7) * cpx + (P >> 3);

    const int e0  = tile * ELB;
    const int rem = min(ELB, n_elem - e0);    // may be <=0 for padded blocks

    if (rem > 0) {
        // ---- stage dN_dx: rem*12 float4s, fully coalesced, nontemporal ----
        const nf4* src = reinterpret_cast<const nf4*>(dN_dx) + (size_t)e0 * 12;
        const int nf4n = rem * 12;
        #pragma unroll
        for (int jj = 0; jj < 3; ++jj) {
            const int m = t + 256 * jj;
            if (m < nf4n) {
                const nf4 v = __builtin_nontemporal_load(src + m);
                *reinterpret_cast<nf4*>(&s_dn[(m / 12) * SLAB + (m % 12) * 4]) = v;
            }
        }
        // ---- stage elements (wave 0) and detJ (wave 1), coalesced, nt ----
        if (t < 64) {
            if (t < rem) {
                const ni4 v = __builtin_nontemporal_load(
                    reinterpret_cast<const ni4*>(elements) + e0 + t);
                reinterpret_cast<ni4*>(s_el)[t] = v;
            }
        } else if (t < 128) {
            const int i = t - 64;
            if (i < rem) {
                const nf4 v = __builtin_nontemporal_load(
                    reinterpret_cast<const nf4*>(detJ) + e0 + i);
                reinterpret_cast<nf4*>(s_dj)[i] = v;
            }
        }
    }
    __syncthreads();

    const int el = t >> 2;
    const int b  = t & 3;
    float a = 0.f;

    if (el < rem) {
        const int4 nd = reinterpret_cast<const int4*>(s_el)[el];

        // gather u: 32-bit offsets; one dwordx4 per node; 4 batch-lanes = one 64B line
        float eu[4][3];
        {
            const float4 v0 = ut[(nd.x << 2) | b];
            const float4 v1 = ut[(nd.y << 2) | b];
            const float4 v2 = ut[(nd.z << 2) | b];
            const float4 v3 = ut[(nd.w << 2) | b];
            eu[0][0]=v0.x; eu[0][1]=v0.y; eu[0][2]=v0.z;
            eu[1][0]=v1.x; eu[1][1]=v1.y; eu[1][2]=v1.z;
            eu[2][0]=v2.x; eu[2][1]=v2.y; eu[2][2]=v2.z;
            eu[3][0]=v3.x; eu[3][1]=v3.y; eu[3][2]=v3.z;
        }

        const float4 w4 = *reinterpret_cast<const float4*>(qw);
        const float* dj = &s_dj[el * 4];
        const float wq[4] = {dj[0]*w4.x, dj[1]*w4.y, dj[2]*w4.z, dj[3]*w4.w};

        const float* slab = &s_dn[el * SLAB];
        #pragma unroll
        for (int q = 0; q < 4; ++q) {
            const float4 f0 = *reinterpret_cast<const float4*>(slab + q*12 + 0);
            const float4 f1 = *reinterpret_cast<const float4*>(slab + q*12 + 4);
            const float4 f2 = *reinterpret_cast<const float4*>(slab + q*12 + 8);
            const float d[12] = {f0.x,f0.y,f0.z,f0.w, f1.x,f1.y,f1.z,f1.w,
                                 f2.x,f2.y,f2.z,f2.w};   // d[n*3 + j]

            float F[3][3];
            #pragma unroll
            for (int i = 0; i < 3; ++i) {
                #pragma unroll
                for (int jj = 0; jj < 3; ++jj) {
                    float g = 0.f;
                    #pragma unroll
                    for (int n = 0; n < 4; ++n)
                        g = fmaf(eu[n][i], d[n*3 + jj], g);
                    F[i][jj] = g + ((i == jj) ? 1.f : 0.f);
                }
            }
            const float J =
                  F[0][0] * (F[1][1]*F[2][2] - F[1][2]*F[2][1])
                - F[0][1] * (F[1][0]*F[2][2] - F[1][2]*F[2][0])
                + F[0][2] * (F[1][0]*F[2][1] - F[1][1]*F[2][0]);

            float IC = 0.f;
            #pragma unroll
            for (int i = 0; i < 3; ++i)
                #pragma unroll
                for (int jj = 0; jj < 3; ++jj)
                    IC = fmaf(F[i][jj], F[i][jj], IC);

            const float lj = __logf(fmaxf(J, EPS_C));
            const float W = 0.5f * MU_C * (IC - 3.f)
                          + 0.25f * LM_C * fmaf(J, J, -1.f)
                          - LOGC * lj;
            a = fmaf(W, wq[q], a);
        }
    }

    // reduce across lanes with same b (stride-4 groups)
    #pragma unroll
    for (int off = 32; off >= 4; off >>= 1)
        a += __shfl_down(a, off);

    const int lane = t & 63;
    const int wid  = t >> 6;
    if (lane < 4) s_red[wid][lane] = a;
    __syncthreads();
    if (t < 4)
        partial[(size_t)P * 4 + t] =
            (s_red[0][t] + s_red[1][t]) + (s_red[2][t] + s_red[3][t]);
}

__global__ __launch_bounds__(256) void nh_final(
    const float* __restrict__ partial, float* __restrict__ out, int nparts)
{
    float accb[4] = {0.f, 0.f, 0.f, 0.f};
    for (int i = threadIdx.x; i < nparts; i += 256) {
        const float4 p = reinterpret_cast<const float4*>(partial)[i];
        accb[0] += p.x; accb[1] += p.y; accb[2] += p.z; accb[3] += p.w;
    }
    #pragma unroll
    for (int b = 0; b < 4; ++b) {
        float v = accb[b];
        #pragma unroll
        for (int off = 32; off > 0; off >>= 1)
            v += __shfl_down(v, off);
        accb[b] = v;
    }
    __shared__ float lds[4][4];
    const int lane = threadIdx.x & 63;
    const int wid  = threadIdx.x >> 6;
    if (lane == 0) {
        #pragma unroll
        for (int b = 0; b < 4; ++b) lds[wid][b] = accb[b];
    }
    __syncthreads();
    if (threadIdx.x == 0) {
        #pragma unroll
        for (int b = 0; b < 4; ++b)
            out[b] = (lds[0][b] + lds[1][b]) + (lds[2][b] + lds[3][b]);
    }
}

extern "C" void kernel_launch(void* const* d_in, const int* in_sizes, int n_in,
                              void* d_out, int out_size, void* d_ws, size_t ws_size,
                              hipStream_t stream) {
    const float* u        = (const float*)d_in[0];
    const int*   elements = (const int*)d_in[1];
    const float* dN_dx    = (const float*)d_in[2];
    const float* detJ     = (const float*)d_in[3];
    const float* qw       = (const float*)d_in[4];
    float* out = (float*)d_out;

    const int B       = out_size;            // 4
    const int n_nodes = in_sizes[0] / (3 * B);
    const int n_elem  = in_sizes[1] / 4;

    const int threads = 256;
    const int ntiles  = (n_elem + ELB - 1) / ELB;
    const int nblocks = (ntiles + 7) & ~7;   // pad to %8==0 for exact swizzle

    const size_t ut_bytes = (size_t)n_nodes * 4 * sizeof(float4);
    float4* ut      = (float4*)d_ws;
    float*  partial = (float*)((char*)d_ws + ut_bytes);

    const int tb = (n_nodes + threads - 1) / threads;
    nh_transpose_u_pad<<<tb, threads, 0, stream>>>(u, ut, n_nodes);

    nh_partial_v14<<<nblocks, threads, 0, stream>>>(ut, elements, dN_dx, detJ, qw,
                                                    partial, n_elem);

    nh_final<<<1, threads, 0, stream>>>(partial, out, nblocks);
}